// Round 1
// 316.294 us; speedup vs baseline: 1.0966x; 1.0966x over previous
//
#include <hip/hip_runtime.h>
#include <stdint.h>

#define S_LEN 2048
#define NH 16
#define DM 1024
#define HD 64
#define NB 2
#define TOK (NB * S_LEN)  // 4096

typedef __attribute__((ext_vector_type(8))) short short8v;  // 8 bf16 = 4 VGPR
typedef __attribute__((ext_vector_type(4))) float f32x4;
typedef __attribute__((ext_vector_type(2))) unsigned int u32x2;
typedef unsigned short u16;
typedef unsigned int u32;

__device__ __forceinline__ float bf2f(u16 u) {
    u32 x = ((u32)u) << 16;
    return __builtin_bit_cast(float, x);
}
__device__ __forceinline__ u16 f2bf(float f) {  // RNE
    u32 u = __builtin_bit_cast(u32, f);
    return (u16)((u + 0x7FFFu + ((u >> 16) & 1u)) >> 16);
}

// async global->LDS, 16B per lane. LDS dest = wave-uniform base + lane*16 (HW).
// Generic LDS pointer = aperture(hi32) | offset(lo32): truncate to 32b offset.
__device__ __forceinline__ void gld_lds16(const void* g, void* lds_base_uniform) {
    auto gp = (const __attribute__((address_space(1))) u32*)(uintptr_t)g;
    auto lp = (__attribute__((address_space(3))) u32*)(uintptr_t)(u32)(uintptr_t)lds_base_uniform;
    __builtin_amdgcn_global_load_lds(gp, lp, 16, 0, 0);
}

// ---------------------------------------------------------------------------
// dtype sniffer: flag=1 if x is bf16, 0 if fp32. Samples low u16 of 4096 u32
// words (bf16 data -> sane exponents ~100%; fp32 data -> random mantissa ~25%).
// ---------------------------------------------------------------------------
__global__ void detect_dtype(const u32* __restrict__ xw, int* __restrict__ flag) {
    __shared__ int cnt[4];
    const int t = threadIdx.x;
    int c = 0;
#pragma unroll
    for (int j = 0; j < 16; ++j) {
        const u32 wd = xw[(t * 16 + j) * 64];  // spread over first 1MB
        const u32 e = (wd >> 7) & 0xFF;        // exponent of LOW u16 as bf16
        c += (e >= 0x58 && e <= 0x98) ? 1 : 0;
    }
#pragma unroll
    for (int off = 1; off < 64; off <<= 1) c += __shfl_xor(c, off);
    if ((t & 63) == 0) cnt[t >> 6] = c;
    __syncthreads();
    if (t == 0) flag[0] = (cnt[0] + cnt[1] + cnt[2] + cnt[3] >= 2600) ? 1 : 0;
}

// ---------------------------------------------------------------------------
// C[m,n] = sum_k A[m,k]*Bt[n,k] + bias[n]; fp32 accum. 128x128 tile, BK=32.
// Per-operand dtype: *_flagged ? (runtime flag: 1=bf16,0=fp32) : always bf16.
// ---------------------------------------------------------------------------
__global__ __launch_bounds__(256) void gemm_bt_bias(
    const void* __restrict__ Av, const void* __restrict__ Btv,
    const void* __restrict__ biasv, void* __restrict__ Cv,
    int M, int N, int K, const int* __restrict__ flagp,
    int a_flagged, int b_flagged, int out_flagged) {
    __shared__ __align__(16) u16 lA[128 * 32];
    __shared__ __align__(16) u16 lB[128 * 32];
    const int fl = flagp[0];
    const int fa = a_flagged ? fl : 1;
    const int fb = b_flagged ? fl : 1;
    const int fo = out_flagged ? fl : 1;

    const int tid = threadIdx.x;
    const int w = __builtin_amdgcn_readfirstlane(tid >> 6);
    const int lane = tid & 63;
    const int quad = lane >> 4;
    const int l16 = lane & 15;
    const int bm = blockIdx.y * 128;
    const int bn = blockIdx.x * 128;
    const int wm = (w >> 1) * 64;
    const int wn = (w & 1) * 64;

    f32x4 acc[4][4];
#pragma unroll
    for (int i = 0; i < 4; ++i)
#pragma unroll
        for (int j = 0; j < 4; ++j) acc[i][j] = {0.f, 0.f, 0.f, 0.f};

    const int kiters = K >> 5;
    for (int kk = 0; kk < kiters; ++kk) {
        __syncthreads();  // previous tile fully consumed
        if (fa) {
            const u16* A = (const u16*)Av;
#pragma unroll
            for (int c = 0; c < 2; ++c) {
                const int chunk = w * 2 + c;
                const int off = chunk * 1024 + lane * 16;  // byte off in 8KB tile
                const int m = off >> 6;
                const int kb = off & 63;
                gld_lds16((const char*)(A + (size_t)(bm + m) * K + kk * 32) + kb,
                          (char*)lA + chunk * 1024);
            }
        } else {
            const float* Af = (const float*)Av;
#pragma unroll
            for (int c = 0; c < 2; ++c) {
                const int e = (w * 2 + c) * 512 + lane * 8;  // element off in tile
                const int m = e >> 5, kc = e & 31;
                const float* ga = Af + (size_t)(bm + m) * K + kk * 32 + kc;
                const f32x4 v0 = *(const f32x4*)ga;
                const f32x4 v1 = *(const f32x4*)(ga + 4);
                short8v o;
#pragma unroll
                for (int q = 0; q < 4; ++q) o[q] = (short)f2bf(v0[q]);
#pragma unroll
                for (int q = 0; q < 4; ++q) o[4 + q] = (short)f2bf(v1[q]);
                *(short8v*)&lA[m * 32 + kc] = o;
            }
        }
        if (fb) {
            const u16* Bt = (const u16*)Btv;
#pragma unroll
            for (int c = 0; c < 2; ++c) {
                const int chunk = w * 2 + c;
                const int off = chunk * 1024 + lane * 16;
                const int m = off >> 6;
                const int kb = off & 63;
                gld_lds16((const char*)(Bt + (size_t)(bn + m) * K + kk * 32) + kb,
                          (char*)lB + chunk * 1024);
            }
        } else {
            const float* Btf = (const float*)Btv;
#pragma unroll
            for (int c = 0; c < 2; ++c) {
                const int e = (w * 2 + c) * 512 + lane * 8;
                const int m = e >> 5, kc = e & 31;
                const float* ga = Btf + (size_t)(bn + m) * K + kk * 32 + kc;
                const f32x4 v0 = *(const f32x4*)ga;
                const f32x4 v1 = *(const f32x4*)(ga + 4);
                short8v o;
#pragma unroll
                for (int q = 0; q < 4; ++q) o[q] = (short)f2bf(v0[q]);
#pragma unroll
                for (int q = 0; q < 4; ++q) o[4 + q] = (short)f2bf(v1[q]);
                *(short8v*)&lB[m * 32 + kc] = o;
            }
        }
        __syncthreads();  // drains vmcnt (async LDS loads) + lgkm + barrier

        short8v af[4], bf[4];
#pragma unroll
        for (int t = 0; t < 4; ++t) {
            af[t] = *(const short8v*)&lA[(wm + t * 16 + l16) * 32 + quad * 8];
            bf[t] = *(const short8v*)&lB[(wn + t * 16 + l16) * 32 + quad * 8];
        }
#pragma unroll
        for (int i = 0; i < 4; ++i)
#pragma unroll
            for (int j = 0; j < 4; ++j)
                acc[i][j] = __builtin_amdgcn_mfma_f32_16x16x32_bf16(af[i], bf[j], acc[i][j], 0, 0, 0);
    }

    // epilogue: C row = quad*4+r, col = lane&15 (m89/m91-verified layout)
#pragma unroll
    for (int j = 0; j < 4; ++j) {
        const int col = bn + wn + j * 16 + l16;
        const float bv = fl ? bf2f(((const u16*)biasv)[col]) : ((const float*)biasv)[col];
#pragma unroll
        for (int i = 0; i < 4; ++i) {
            const int row0 = bm + wm + i * 16 + quad * 4;
#pragma unroll
            for (int r = 0; r < 4; ++r) {
                const float val = acc[i][j][r] + bv;
                const size_t idx = (size_t)(row0 + r) * N + col;
                if (fo) ((u16*)Cv)[idx] = f2bf(val);
                else ((float*)Cv)[idx] = val;
            }
        }
    }
}

// ---------------------------------------------------------------------------
// RoPE on q,k + reorder to (B,H,S,64). One thread per rotation pair.
// ---------------------------------------------------------------------------
__global__ __launch_bounds__(256) void rope_reorder(
    const u16* __restrict__ qkv, u16* __restrict__ qws, u16* __restrict__ kws) {
    const int idx = blockIdx.x * 256 + threadIdx.x;  // B*S*H*32 = 2^21
    const int i = idx & 31;
    const int h = (idx >> 5) & 15;
    const int s = (idx >> 9) & 2047;
    const int b = idx >> 20;
    const u16* src = qkv + ((size_t)(b * S_LEN + s)) * (3 * DM) + h * HD + 2 * i;
    const u32 qp = *(const u32*)(src);
    const u32 kp = *(const u32*)(src + DM);
    const float q1 = bf2f((u16)qp), q2 = bf2f((u16)(qp >> 16));
    const float k1 = bf2f((u16)kp), k2 = bf2f((u16)(kp >> 16));
    const float freq = expf(-(float)(2 * i) * 0.14391156831212787f);  // 10000^(-2i/64)
    const float th = (float)s * freq;
    float sn, cs;
    sincosf(th, &sn, &cs);
    const float oq1 = q1 * cs - q2 * sn, oq2 = q1 * sn + q2 * cs;
    const float ok1 = k1 * cs - k2 * sn, ok2 = k1 * sn + k2 * cs;
    const size_t dst = ((size_t)((b * NH + h) * S_LEN + s)) * HD + 2 * i;
    *(u32*)(qws + dst) = (u32)f2bf(oq1) | ((u32)f2bf(oq2) << 16);
    *(u32*)(kws + dst) = (u32)f2bf(ok1) | ((u32)f2bf(ok2) << 16);
}

// ---------------------------------------------------------------------------
// V -> V^T (B,H,64,S) via padded LDS tile (PV A-operand must be K-contiguous)
// ---------------------------------------------------------------------------
__global__ __launch_bounds__(256) void v_transpose(
    const u16* __restrict__ qkv, u16* __restrict__ vT) {
    __shared__ u16 tile[64 * 65];
    const int s0 = blockIdx.x * 64;
    const int h = blockIdx.y, b = blockIdx.z;
    const int t = threadIdx.x;
#pragma unroll
    for (int it = 0; it < 16; ++it) {
        const int e = t + 256 * it;
        const int sl = e >> 6, d = e & 63;
        tile[sl * 65 + d] =
            qkv[((size_t)(b * S_LEN + s0 + sl)) * (3 * DM) + 2 * DM + h * HD + d];
    }
    __syncthreads();
#pragma unroll
    for (int it = 0; it < 16; ++it) {
        const int e = t + 256 * it;
        const int d = e >> 6, sl = e & 63;
        vT[((size_t)((b * NH + h) * HD + d)) * S_LEN + s0 + sl] = tile[sl * 65 + d];
    }
}

// ---------------------------------------------------------------------------
// Flash attention, swapped-operand form. Block = 4 waves; wave handles 2
// q-strips of 16 rows (q0, q0+64) sharing K/V fragment loads. Sk tile = 32.
//
// QK^T is computed TRANSPOSED: S^T = mfma(K_frag, Q_frag) so each lane holds
// 8 scores of ONE q-row (q = lane&15) in registers -> row max/sum are 7
// in-lane VALU ops + shfl_xor(16) + shfl_xor(32) (2 cross-lane ops instead of
// 4-deep shuffle chains per row; 64 -> 8 cross-lane ops per kt iteration).
// m/l/alpha are one scalar per strip. P is packed to bf16 pairs in-register
// and staged via 2x ds_write_b64 per strip into a stride-20-u32 padded layout
// (bank-uniform for both b64 writes and b128 B-frag reads).
// PV is accumulated transposed: O^T = mfma(V^T_frag, P_frag) - V fragments
// are identical to before (V^T is K-contiguous); alpha rescale is a per-lane
// scalar broadcast. Causal.
// ---------------------------------------------------------------------------
__global__ __launch_bounds__(256) void attn_kernel(
    const u16* __restrict__ qws, const u16* __restrict__ kws,
    const u16* __restrict__ vT, u16* __restrict__ ows) {
    // per-wave private P staging: [wave][strip][16 q-rows][20 u32 (16 + pad)]
    __shared__ __align__(16) u32 pl32[4][2][16 * 20];  // 10240 B
    const int t = threadIdx.x;
    const int w = __builtin_amdgcn_readfirstlane(t >> 6);
    const int lane = t & 63;
    const int quad = lane >> 4;
    const int l16 = lane & 15;
    const int h = blockIdx.y, b = blockIdx.z;

    int q0[2];
    q0[0] = blockIdx.x * 128 + w * 16;
    q0[1] = q0[0] + 64;

    const size_t bh = (size_t)(b * NH + h);
    const u16* qb = qws + bh * (size_t)S_LEN * HD;
    const u16* kb = kws + bh * (size_t)S_LEN * HD;
    const u16* vb = vT + bh * (size_t)HD * S_LEN;

    short8v qf[2][2];
#pragma unroll
    for (int st = 0; st < 2; ++st)
#pragma unroll
        for (int hf = 0; hf < 2; ++hf)
            qf[st][hf] = *(const short8v*)(qb + (size_t)(q0[st] + l16) * HD + hf * 32 + quad * 8);

    f32x4 oaccT[2][4];  // [strip][d-frag]: row = d (quad*4+r), col = q (l16)
    float mrow[2], lrow[2];
#pragma unroll
    for (int st = 0; st < 2; ++st) {
#pragma unroll
        for (int d = 0; d < 4; ++d) oaccT[st][d] = {0.f, 0.f, 0.f, 0.f};
        mrow[st] = -__builtin_inff();
        lrow[st] = 0.f;
    }

    const int ktl[2] = {(q0[0] + 15) >> 5, (q0[1] + 15) >> 5};

    for (int kt = 0; kt <= ktl[1]; ++kt) {
        short8v kf[2][2];  // shared by both strips
#pragma unroll
        for (int sub = 0; sub < 2; ++sub)
#pragma unroll
            for (int hf = 0; hf < 2; ++hf)
                kf[sub][hf] = *(const short8v*)(kb + (size_t)(kt * 32 + sub * 16 + l16) * HD +
                                                hf * 32 + quad * 8);

#pragma unroll
        for (int st = 0; st < 2; ++st) {
            if (kt > ktl[st]) continue;
            const f32x4 z = {0.f, 0.f, 0.f, 0.f};
            // S^T tiles: row = k (quad*4+r), col = q (l16)
            f32x4 s0 = __builtin_amdgcn_mfma_f32_16x16x32_bf16(kf[0][0], qf[st][0], z, 0, 0, 0);
            s0 = __builtin_amdgcn_mfma_f32_16x16x32_bf16(kf[0][1], qf[st][1], s0, 0, 0, 0);
            f32x4 s1 = __builtin_amdgcn_mfma_f32_16x16x32_bf16(kf[1][0], qf[st][0], z, 0, 0, 0);
            s1 = __builtin_amdgcn_mfma_f32_16x16x32_bf16(kf[1][1], qf[st][1], s1, 0, 0, 0);

            const int qg = q0[st] + l16;
            float sv[8];
#pragma unroll
            for (int r = 0; r < 4; ++r) {
                sv[r] = s0[r] * 0.125f;
                sv[4 + r] = s1[r] * 0.125f;
            }
            if (kt == ktl[st]) {  // diagonal tile: mask k > q
                const int kbase = kt * 32 + quad * 4;
#pragma unroll
                for (int r = 0; r < 4; ++r) {
                    if (kbase + r > qg) sv[r] = -__builtin_inff();
                    if (kbase + 16 + r > qg) sv[4 + r] = -__builtin_inff();
                }
            }
            // row (per-q) max: 7 in-lane + 2 cross-lane
            float mx = fmaxf(sv[0], sv[1]);
            mx = fmaxf(mx, fmaxf(sv[2], sv[3]));
            mx = fmaxf(mx, fmaxf(sv[4], sv[5]));
            mx = fmaxf(mx, fmaxf(sv[6], sv[7]));
            mx = fmaxf(mx, __shfl_xor(mx, 16));
            mx = fmaxf(mx, __shfl_xor(mx, 32));
            const float mnew = fmaxf(mrow[st], mx);
            const float alpha = __expf(mrow[st] - mnew);
            mrow[st] = mnew;
            float p[8], ps = 0.f;
#pragma unroll
            for (int j = 0; j < 8; ++j) {
                p[j] = __expf(sv[j] - mnew);
                ps += p[j];
            }
            ps += __shfl_xor(ps, 16);
            ps += __shfl_xor(ps, 32);
            lrow[st] = lrow[st] * alpha + ps;
#pragma unroll
            for (int d = 0; d < 4; ++d) oaccT[st][d] *= alpha;
            // pack P[q=l16][k] to bf16 pairs; 2x b64 writes
            u32* row = &pl32[w][st][l16 * 20];
            u32x2 lo, hi;
            lo.x = (u32)f2bf(p[0]) | ((u32)f2bf(p[1]) << 16);
            lo.y = (u32)f2bf(p[2]) | ((u32)f2bf(p[3]) << 16);
            hi.x = (u32)f2bf(p[4]) | ((u32)f2bf(p[5]) << 16);
            hi.y = (u32)f2bf(p[6]) | ((u32)f2bf(p[7]) << 16);
            *(u32x2*)&row[2 * quad] = lo;       // k = 4*quad .. 4*quad+3
            *(u32x2*)&row[8 + 2 * quad] = hi;   // k = 16+4*quad .. 16+4*quad+3
        }
        __threadfence_block();  // wave-private LDS; DS ops in-order per wave
        short8v vf[4];
#pragma unroll
        for (int d = 0; d < 4; ++d)
            vf[d] = *(const short8v*)(vb + (size_t)(d * 16 + l16) * S_LEN + kt * 32 + quad * 8);
#pragma unroll
        for (int st = 0; st < 2; ++st) {
            if (kt > ktl[st]) continue;
            // B-frag: lane (quad, l16=q) reads P[q][8*quad .. 8*quad+7]
            const short8v pf = *(const short8v*)&pl32[w][st][l16 * 20 + 4 * quad];
#pragma unroll
            for (int d = 0; d < 4; ++d)
                oaccT[st][d] = __builtin_amdgcn_mfma_f32_16x16x32_bf16(vf[d], pf, oaccT[st][d], 0, 0, 0);
        }
    }

    // epilogue: O[q][d] with q = q0+l16, d = df*16 + quad*4 + r -> 8B packed stores
#pragma unroll
    for (int st = 0; st < 2; ++st) {
        const float inv = 1.0f / lrow[st];
        const size_t rowbase = ((size_t)(b * S_LEN + q0[st] + l16)) * DM + h * HD;
#pragma unroll
        for (int df = 0; df < 4; ++df) {
            const int d0 = df * 16 + quad * 4;
            u32x2 ov;
            ov.x = (u32)f2bf(oaccT[st][df][0] * inv) | ((u32)f2bf(oaccT[st][df][1] * inv) << 16);
            ov.y = (u32)f2bf(oaccT[st][df][2] * inv) | ((u32)f2bf(oaccT[st][df][3] * inv) << 16);
            *(u32x2*)(ows + rowbase + d0) = ov;
        }
    }
}

extern "C" void kernel_launch(void* const* d_in, const int* in_sizes, int n_in,
                              void* d_out, int out_size, void* d_ws, size_t ws_size,
                              hipStream_t stream) {
    const void* x = d_in[0];
    const void* w_qkv = d_in[1];
    const void* b_qkv = d_in[2];
    const void* w_out = d_in[3];
    const void* b_out = d_in[4];

    int* flag = (int*)d_ws;
    u16* qkv = (u16*)d_ws + 8;                      // 16B-aligned
    u16* qws = qkv + (size_t)TOK * 3 * DM;          // (B,H,S,64)
    u16* kws = qws + (size_t)NB * NH * S_LEN * HD;
    u16* vT = kws + (size_t)NB * NH * S_LEN * HD;   // (B,H,64,S)
    u16* ows = qkv;  // alias: qkv dead after rope_reorder + v_transpose

    detect_dtype<<<1, 256, 0, stream>>>((const u32*)x, flag);
    gemm_bt_bias<<<dim3(3 * DM / 128, TOK / 128), 256, 0, stream>>>(
        x, w_qkv, b_qkv, qkv, TOK, 3 * DM, DM, flag, 1, 1, 0);
    rope_reorder<<<(NB * S_LEN * NH * 32) / 256, 256, 0, stream>>>(qkv, qws, kws);
    v_transpose<<<dim3(S_LEN / 64, NH, NB), 256, 0, stream>>>(qkv, vT);
    attn_kernel<<<dim3(S_LEN / 128, NH, NB), 256, 0, stream>>>(qws, kws, vT, ows);
    gemm_bt_bias<<<dim3(DM / 128, TOK / 128), 256, 0, stream>>>(
        ows, w_out, b_out, d_out, TOK, DM, DM, flag, 0, 1, 1);
}